// Round 2
// baseline (1871.609 us; speedup 1.0000x reference)
//
#include <hip/hip_runtime.h>

#define BDIM 2
#define SEQ  1568
#define DIM  768
#define NH   12
#define FR   8
#define NTOK 196
#define HD   64
#define MTOT (BDIM*SEQ)   // 3136 rows total

static __device__ __forceinline__ float bf2f(ushort u) {
  return __uint_as_float(((unsigned)u) << 16);
}
static __device__ __forceinline__ ushort f2bf(float f) {
  unsigned u = __float_as_uint(f);
  unsigned r = (u + 0x7fffu + ((u >> 16) & 1u)) >> 16;
  return (ushort)r;
}

// ---------------------------------------------------------------------------
// Generic fp32 tiled GEMM: C[M x N] = scale * (A[M x K] @ B[K x N]) (+ bias)
// DIAG variant: A row r is gathered from bf16 x buffer at frame r%SEQ/NTOK.
// Tile 64x64, BK=16, 256 threads, 4x4 per thread. All dims divide evenly.
// ---------------------------------------------------------------------------
template<bool BIAS, bool DIAG>
__global__ __launch_bounds__(256)
void gemm_k(const float* __restrict__ A, const ushort* __restrict__ Abf,
            const float* __restrict__ Bw, float* __restrict__ C,
            const float* __restrict__ bias, int N, int K, float scale)
{
  __shared__ float As[16][64];
  __shared__ float Bs[16][68];
  const int tid = threadIdx.x;
  const int bx = blockIdx.x, by = blockIdx.y;
  const int tx = tid & 15, ty = tid >> 4;
  const int arow = tid >> 2, acol4 = (tid & 3) << 2;
  const int brow = tid >> 4, bcol4 = (tid & 15) << 2;
  const int rowA = by*64 + arow;

  const float*  Aptr = nullptr;
  const ushort* Aptr_bf = nullptr;
  if (DIAG) {
    int fr = (rowA % SEQ) / NTOK;
    Aptr_bf = Abf + ((size_t)rowA*FR + fr)*DIM + acol4;
  } else {
    Aptr = A + (size_t)rowA*K + acol4;
  }
  const float* Bptr = Bw + (size_t)brow*N + bx*64 + bcol4;

  float acc[4][4] = {};

  for (int k0 = 0; k0 < K; k0 += 16) {
    float4 av;
    if (DIAG) {
      ushort4 a4 = *(const ushort4*)(Aptr_bf + k0);
      av.x = bf2f(a4.x); av.y = bf2f(a4.y); av.z = bf2f(a4.z); av.w = bf2f(a4.w);
    } else {
      av = *(const float4*)(Aptr + k0);
    }
    float4 bv = *(const float4*)(Bptr + (size_t)k0*N);
    __syncthreads();
    As[acol4+0][arow] = av.x;
    As[acol4+1][arow] = av.y;
    As[acol4+2][arow] = av.z;
    As[acol4+3][arow] = av.w;
    *(float4*)&Bs[brow][bcol4] = bv;
    __syncthreads();
    #pragma unroll
    for (int kk = 0; kk < 16; kk++) {
      float4 a = *(const float4*)&As[kk][ty<<2];
      float4 b = *(const float4*)&Bs[kk][tx<<2];
      acc[0][0] += a.x*b.x; acc[0][1] += a.x*b.y; acc[0][2] += a.x*b.z; acc[0][3] += a.x*b.w;
      acc[1][0] += a.y*b.x; acc[1][1] += a.y*b.y; acc[1][2] += a.y*b.z; acc[1][3] += a.y*b.w;
      acc[2][0] += a.z*b.x; acc[2][1] += a.z*b.y; acc[2][2] += a.z*b.z; acc[2][3] += a.z*b.w;
      acc[3][0] += a.w*b.x; acc[3][1] += a.w*b.y; acc[3][2] += a.w*b.z; acc[3][3] += a.w*b.w;
    }
  }

  const int row0 = by*64 + (ty<<2);
  const int col0 = bx*64 + (tx<<2);
  #pragma unroll
  for (int i = 0; i < 4; i++) {
    float4 v;
    v.x = acc[i][0]*scale; v.y = acc[i][1]*scale;
    v.z = acc[i][2]*scale; v.w = acc[i][3]*scale;
    if (BIAS) {
      v.x += bias[col0+0]; v.y += bias[col0+1];
      v.z += bias[col0+2]; v.w += bias[col0+3];
    }
    *(float4*)&C[(size_t)(row0+i)*N + col0] = v;
  }
}

// ---------------------------------------------------------------------------
// Stage 1: per-frame spatial attention.
// grid: (8 query tiles, F frames, B*H). One wave = one query at a time.
// K/V for (b,h,f) staged in LDS as bf16. Output x (b,s,f,DIM) as bf16.
// ---------------------------------------------------------------------------
__global__ __launch_bounds__(256)
void stage1_attn(const float* __restrict__ q, const float* __restrict__ kv,
                 ushort* __restrict__ x)
{
  __shared__ ushort Ks[NTOK][68];
  __shared__ ushort Vs[NTOK][68];
  __shared__ float  qbuf[4][64];
  __shared__ float  abuf[4][208];

  const int qtile = blockIdx.x;          // 0..7
  const int f     = blockIdx.y;          // 0..7
  const int bh    = blockIdx.z;          // 0..23
  const int b = bh / NH, h = bh % NH;
  const int tid = threadIdx.x;

  const size_t kvrow0 = (size_t)b*SEQ + (size_t)f*NTOK;
  for (int idx = tid; idx < NTOK*16; idx += 256) {
    int row = idx >> 4, c4 = (idx & 15) << 2;
    const float* kp = kv + (kvrow0 + row)*(2*DIM) + h*HD + c4;
    float4 kvv = *(const float4*)kp;
    float4 vvv = *(const float4*)(kp + DIM);
    ushort4 ku; ku.x = f2bf(kvv.x); ku.y = f2bf(kvv.y); ku.z = f2bf(kvv.z); ku.w = f2bf(kvv.w);
    ushort4 vu; vu.x = f2bf(vvv.x); vu.y = f2bf(vvv.y); vu.z = f2bf(vvv.z); vu.w = f2bf(vvv.w);
    *(ushort4*)&Ks[row][c4] = ku;
    *(ushort4*)&Vs[row][c4] = vu;
  }
  __syncthreads();

  const int w = tid >> 6, lane = tid & 63;
  for (int qi = w; qi < 196; qi += 4) {
    const int s = qtile*196 + qi;
    const float* qg = q + ((size_t)b*SEQ + s)*DIM + h*HD;
    qbuf[w][lane] = qg[lane];

    float lv[4]; int nj = 0;
    for (int j = lane; j < NTOK; j += 64) {
      float dot = 0.f;
      #pragma unroll
      for (int d4 = 0; d4 < 64; d4 += 4) {
        ushort4 k4 = *(const ushort4*)&Ks[j][d4];
        float4 qq = *(const float4*)&qbuf[w][d4];
        dot += bf2f(k4.x)*qq.x + bf2f(k4.y)*qq.y + bf2f(k4.z)*qq.z + bf2f(k4.w)*qq.w;
      }
      lv[nj++] = dot * 0.125f;
    }
    float m = -1e30f;
    for (int i = 0; i < nj; i++) m = fmaxf(m, lv[i]);
    #pragma unroll
    for (int off = 32; off > 0; off >>= 1) m = fmaxf(m, __shfl_xor(m, off));
    float ssum = 0.f;
    for (int i = 0; i < nj; i++) {
      float e = __expf(lv[i] - m);
      abuf[w][lane + (i << 6)] = e;
      ssum += e;
    }
    #pragma unroll
    for (int off = 32; off > 0; off >>= 1) ssum += __shfl_xor(ssum, off);
    const float inv = 1.0f / ssum;

    float acc = 0.f;
    #pragma unroll 4
    for (int j4 = 0; j4 < 196; j4 += 4) {
      float4 a4 = *(const float4*)&abuf[w][j4];
      acc += a4.x*bf2f(Vs[j4+0][lane]) + a4.y*bf2f(Vs[j4+1][lane])
           + a4.z*bf2f(Vs[j4+2][lane]) + a4.w*bf2f(Vs[j4+3][lane]);
    }
    x[(((size_t)b*SEQ + s)*FR + f)*DIM + h*HD + lane] = f2bf(acc * inv);
  }
}

// ---------------------------------------------------------------------------
// Stage 2 fused (u-trick): per (16-token tile, head h)
//   u[t][j]   = sum_d Wpkv_k[j, h64+d] * q2[t, h64+d]
//   lg[t][f]  = sum_j x[t,f,j] * u[t][j]        -> softmax -> attn2 (output)
//   y[t][j]   = sum_f a2[t][f] * x[t,f,j]       (reuses u's LDS)
//   z[t][h64+d] = sum_j y[t][j] * Wpkv_v[j, h64+d]
// ---------------------------------------------------------------------------
__global__ __launch_bounds__(256)
void stage2_fused(const float* __restrict__ q2, const ushort* __restrict__ xbf,
                  const float* __restrict__ Wpkv, float* __restrict__ z,
                  float* __restrict__ attn2)
{
  __shared__ float q2s[16][64];
  __shared__ float u[16][772];    // padded stride: bank = (4t + j) % 32
  __shared__ float lg[16][8];
  __shared__ float a2[16][8];

  const int st = blockIdx.x;      // token tile
  const int h  = blockIdx.y;
  const int tid = threadIdx.x;
  const int r0 = st * 16;

  for (int i = tid; i < 16*64; i += 256) {
    int t = i >> 6, d = i & 63;
    q2s[t][d] = q2[(size_t)(r0 + t)*DIM + h*HD + d];
  }
  __syncthreads();

  // ---- u ----
  {
    float acc0[16] = {}, acc1[16] = {}, acc2[16] = {};
    const size_t cb = (size_t)h*HD;
    #pragma unroll 4
    for (int d4 = 0; d4 < 64; d4 += 4) {
      float4 w0 = *(const float4*)&Wpkv[(size_t)(tid      )*(2*DIM) + cb + d4];
      float4 w1 = *(const float4*)&Wpkv[(size_t)(tid + 256)*(2*DIM) + cb + d4];
      float4 w2 = *(const float4*)&Wpkv[(size_t)(tid + 512)*(2*DIM) + cb + d4];
      #pragma unroll
      for (int t = 0; t < 16; t++) {
        float4 qv = *(const float4*)&q2s[t][d4];
        acc0[t] += w0.x*qv.x + w0.y*qv.y + w0.z*qv.z + w0.w*qv.w;
        acc1[t] += w1.x*qv.x + w1.y*qv.y + w1.z*qv.z + w1.w*qv.w;
        acc2[t] += w2.x*qv.x + w2.y*qv.y + w2.z*qv.z + w2.w*qv.w;
      }
    }
    #pragma unroll
    for (int t = 0; t < 16; t++) {
      u[t][tid      ] = acc0[t];
      u[t][tid + 256] = acc1[t];
      u[t][tid + 512] = acc2[t];
    }
  }
  __syncthreads();

  // ---- logits ----
  if (tid < 128) {
    int t = tid >> 3, f = tid & 7;
    const ushort* xr = xbf + ((size_t)(r0 + t)*FR + f)*DIM;
    float s = 0.f;
    for (int j = 0; j < DIM; j += 4) {
      ushort4 xv = *(const ushort4*)(xr + j);
      float4 uv = *(const float4*)&u[t][j];
      s += bf2f(xv.x)*uv.x + bf2f(xv.y)*uv.y + bf2f(xv.z)*uv.z + bf2f(xv.w)*uv.w;
    }
    lg[t][f] = s;
  }
  __syncthreads();

  // ---- softmax + attn2 output ----
  if (tid < 16) {
    int t = tid, r = r0 + t;
    int b = r / SEQ, s_ = r % SEQ;
    float m = lg[t][0];
    #pragma unroll
    for (int f = 1; f < 8; f++) m = fmaxf(m, lg[t][f]);
    float e[8]; float sum = 0.f;
    #pragma unroll
    for (int f = 0; f < 8; f++) { e[f] = __expf(lg[t][f] - m); sum += e[f]; }
    float inv = 1.0f / sum;
    float* ao = attn2 + ((size_t)(b*NH + h)*SEQ + s_)*FR;
    #pragma unroll
    for (int f = 0; f < 8; f++) { float a = e[f]*inv; a2[t][f] = a; ao[f] = a; }
  }
  __syncthreads();

  // ---- y (reuse u) ----
  {
    int t = tid >> 4, seg = tid & 15;
    int j0 = seg * 48;
    float yl[48] = {};
    #pragma unroll
    for (int f = 0; f < 8; f++) {
      float af = a2[t][f];
      const ushort* xr = xbf + ((size_t)(r0 + t)*FR + f)*DIM + j0;
      for (int jj = 0; jj < 48; jj += 4) {
        ushort4 xv = *(const ushort4*)(xr + jj);
        yl[jj+0] += af*bf2f(xv.x); yl[jj+1] += af*bf2f(xv.y);
        yl[jj+2] += af*bf2f(xv.z); yl[jj+3] += af*bf2f(xv.w);
      }
    }
    for (int jj = 0; jj < 48; jj++) u[t][j0 + jj] = yl[jj];
  }
  __syncthreads();

  // ---- z ----
  {
    int t = tid >> 4, dq = tid & 15;
    const float* wv = Wpkv + DIM + (size_t)h*HD + dq*4;
    float zx = 0.f, zy = 0.f, zz = 0.f, zw = 0.f;
    #pragma unroll 4
    for (int j = 0; j < DIM; j++) {
      float4 w4 = *(const float4*)(wv + (size_t)j*(2*DIM));
      float yv = u[t][j];
      zx += yv*w4.x; zy += yv*w4.y; zz += yv*w4.z; zw += yv*w4.w;
    }
    float4 o; o.x = zx; o.y = zy; o.z = zz; o.w = zw;
    *(float4*)&z[(size_t)(r0 + t)*DIM + h*HD + dq*4] = o;
  }
}

// ---------------------------------------------------------------------------
// Workspace layout (peak 67.4 MB; aliased to stay well under ws_size):
//   [xbf: 3136*8*768 bf16 = 38.5 MB][q/q2: 9.6 MB fp32][kv/z: 19.3 MB fp32]
// q is dead after stage1 -> q2 reuses it; kv dead after stage1 -> z reuses it.
// ---------------------------------------------------------------------------
extern "C" void kernel_launch(void* const* d_in, const int* in_sizes, int n_in,
                              void* d_out, int out_size, void* d_ws, size_t ws_size,
                              hipStream_t stream) {
  const float* xq    = (const float*)d_in[0];
  const float* xk    = (const float*)d_in[1];
  const float* Wq    = (const float*)d_in[2];
  const float* Wkv   = (const float*)d_in[3];
  const float* Wpq   = (const float*)d_in[4];
  const float* Wpkv  = (const float*)d_in[5];
  const float* Wproj = (const float*)d_in[6];
  const float* bproj = (const float*)d_in[7];

  float* out   = (float*)d_out;
  float* attn2 = out + (size_t)MTOT*DIM;

  ushort* xbf = (ushort*)d_ws;                          // 3136*8*768 bf16
  float*  q   = (float*)(xbf + (size_t)MTOT*FR*DIM);    // 3136*768  fp32
  float*  kv  = q + (size_t)MTOT*DIM;                   // 3136*1536 fp32
  float*  q2  = q;    // alias: q dead after stage1
  float*  z   = kv;   // alias: kv dead after stage1

  dim3 blk(256);
  // q = xq @ Wq
  gemm_k<false,false><<<dim3(DIM/64, MTOT/64), blk, 0, stream>>>(
      xq, nullptr, Wq, q, nullptr, DIM, DIM, 1.0f);
  // kv = xk @ Wkv
  gemm_k<false,false><<<dim3(2*DIM/64, MTOT/64), blk, 0, stream>>>(
      xk, nullptr, Wkv, kv, nullptr, 2*DIM, DIM, 1.0f);
  // stage 1 attention -> x (bf16)
  stage1_attn<<<dim3(8, FR, BDIM*NH), blk, 0, stream>>>(q, kv, xbf);
  // q2 = scale * (x_diag @ Wpq)   (diagonal gather folded into A-load)
  gemm_k<false,true><<<dim3(DIM/64, MTOT/64), blk, 0, stream>>>(
      nullptr, xbf, Wpq, q2, nullptr, DIM, DIM, 0.125f);
  // stage 2 fused -> z, attn2
  stage2_fused<<<dim3(MTOT/16, NH), blk, 0, stream>>>(q2, xbf, Wpkv, z, attn2);
  // out = z @ Wproj + bproj
  gemm_k<true,false><<<dim3(DIM/64, MTOT/64), blk, 0, stream>>>(
      z, nullptr, Wproj, out, bproj, DIM, DIM, 1.0f);
}

// Round 3
// 847.701 us; speedup vs baseline: 2.2079x; 2.2079x over previous
//
#include <hip/hip_runtime.h>

#define BDIM 2
#define SEQ  1568
#define DIM  768
#define NH   12
#define FR   8
#define NTOK 196
#define HD   64
#define MTOT (BDIM*SEQ)   // 3136 rows total

typedef __attribute__((ext_vector_type(8))) short s16x8;   // 8 bf16 = 4 VGPRs
typedef __attribute__((ext_vector_type(4))) float f32x4;

static __device__ __forceinline__ float bf2f(ushort u) {
  return __uint_as_float(((unsigned)u) << 16);
}
static __device__ __forceinline__ ushort f2bf(float f) {
  unsigned u = __float_as_uint(f);
  unsigned r = (u + 0x7fffu + ((u >> 16) & 1u)) >> 16;
  return (ushort)r;
}
static __device__ __forceinline__ f32x4 mfma16(s16x8 a, s16x8 b, f32x4 c) {
  return __builtin_amdgcn_mfma_f32_16x16x32_bf16(a, b, c, 0, 0, 0);
}

// ---------------------------------------------------------------------------
// fp32 -> bf16 elementwise (vectorized)
// ---------------------------------------------------------------------------
__global__ __launch_bounds__(256)
void cvt_bf16(const float* __restrict__ in, ushort* __restrict__ out, int n4) {
  int i = blockIdx.x*256 + threadIdx.x;
  if (i < n4) {
    float4 v = ((const float4*)in)[i];
    ushort4 o; o.x = f2bf(v.x); o.y = f2bf(v.y); o.z = f2bf(v.z); o.w = f2bf(v.w);
    ((ushort4*)out)[i] = o;
  }
}

// ---------------------------------------------------------------------------
// Weight transpose + bf16: WT[N][K] = bf16(W[K][N]); 64x64 tiles via LDS.
// grid (N/64, K/64)
// ---------------------------------------------------------------------------
__global__ __launch_bounds__(256)
void cvt_wT(const float* __restrict__ W, ushort* __restrict__ WT, int N, int K) {
  __shared__ float T[64][65];
  const int tid = threadIdx.x;
  const int nx = blockIdx.x, ky = blockIdx.y;
  #pragma unroll
  for (int it = 0; it < 4; it++) {
    int idx = it*256 + tid;
    int r = idx >> 4, c4 = (idx & 15) << 2;
    float4 v = *(const float4*)&W[(size_t)(ky*64 + r)*N + nx*64 + c4];
    T[r][c4+0] = v.x; T[r][c4+1] = v.y; T[r][c4+2] = v.z; T[r][c4+3] = v.w;
  }
  __syncthreads();
  #pragma unroll
  for (int it = 0; it < 4; it++) {
    int idx = it*256 + tid;
    int n = idx >> 4, k4 = (idx & 15) << 2;
    ushort4 o;
    o.x = f2bf(T[k4+0][n]); o.y = f2bf(T[k4+1][n]);
    o.z = f2bf(T[k4+2][n]); o.w = f2bf(T[k4+3][n]);
    *(ushort4*)&WT[(size_t)(nx*64 + n)*K + ky*64 + k4] = o;
  }
}

// ---------------------------------------------------------------------------
// V transpose: Vt[(b,f,h)][64][224] bf16, zero-padded n>=196, from kv_bf.
// grid = 192 (= b*96 + f*12 + h)
// ---------------------------------------------------------------------------
__global__ __launch_bounds__(256)
void vtrans(const ushort* __restrict__ kvbf, ushort* __restrict__ Vt) {
  __shared__ ushort Vl[NTOK][72];
  const int x = blockIdx.x;
  const int h = x % NH, f = (x / NH) % FR, b = x / (NH*FR);
  const int tid = threadIdx.x;
  for (int idx = tid; idx < NTOK*16; idx += 256) {
    int n = idx >> 4, c4 = (idx & 15) << 2;
    const ushort* p = kvbf + (size_t)(b*SEQ + f*NTOK + n)*(2*DIM) + DIM + h*HD + c4;
    *(ushort4*)&Vl[n][c4] = *(const ushort4*)p;
  }
  __syncthreads();
  ushort* vb = Vt + (size_t)x * (HD*224);
  for (int idx = tid; idx < 64*56; idx += 256) {
    int d = idx / 56, n4 = (idx % 56) << 2;
    ushort4 o;
    o.x = (n4+0 < NTOK) ? Vl[n4+0][d] : (ushort)0;
    o.y = (n4+1 < NTOK) ? Vl[n4+1][d] : (ushort)0;
    o.z = (n4+2 < NTOK) ? Vl[n4+2][d] : (ushort)0;
    o.w = (n4+3 < NTOK) ? Vl[n4+3][d] : (ushort)0;
    *(ushort4*)&vb[(size_t)d*224 + n4] = o;
  }
}

// ---------------------------------------------------------------------------
// bf16 MFMA GEMM: C[M x N] = scale*(A[M x K] @ B[K x N]) (+bias)
// A row-major bf16 [M][K]; Bt is B transposed [N][K] bf16 (k-contiguous).
// DIAG: A row r gathered from xbf at frame (r%SEQ)/NTOK.
// Tile 128x128, BK=32, 256 threads (2x2 waves, each 4x4 MFMA 16x16 tiles).
// N must be a multiple of 128; M handled with clamp+predicated store.
// ---------------------------------------------------------------------------
template<bool OUT_BF16, bool BIAS, bool DIAG>
__global__ __launch_bounds__(256)
void gemm_mfma(const ushort* __restrict__ A, const ushort* __restrict__ Bt,
               void* __restrict__ Cv, const float* __restrict__ bias,
               int M, int N, int K, float scale)
{
  __shared__ ushort As[128][56];   // stride 56: 112B rows, 16B-aligned, ~2-way banks
  __shared__ ushort Bs[128][56];
  const int tid = threadIdx.x;
  const int bx = blockIdx.x, by = blockIdx.y;
  const int w = tid >> 6, lane = tid & 63;
  const int lq = lane & 15, quad = lane >> 4;
  const int wr = (w >> 1) * 64, wc = (w & 1) * 64;

  const int lrow = tid >> 2, lcol = (tid & 3) << 3;
  int ar0 = by*128 + lrow;       if (ar0 > M-1) ar0 = M-1;
  int ar1 = by*128 + 64 + lrow;  if (ar1 > M-1) ar1 = M-1;
  size_t aoff0, aoff1;
  if (DIAG) {
    int f0 = (ar0 % SEQ) / NTOK, f1 = (ar1 % SEQ) / NTOK;
    aoff0 = ((size_t)ar0*FR + f0)*DIM + lcol;
    aoff1 = ((size_t)ar1*FR + f1)*DIM + lcol;
  } else {
    aoff0 = (size_t)ar0*K + lcol;
    aoff1 = (size_t)ar1*K + lcol;
  }
  const size_t boff0 = (size_t)(bx*128 + lrow)*K + lcol;
  const size_t boff1 = (size_t)(bx*128 + 64 + lrow)*K + lcol;

  f32x4 acc[4][4] = {};

  for (int k0 = 0; k0 < K; k0 += 32) {
    s16x8 a0 = *(const s16x8*)(A  + aoff0 + k0);
    s16x8 a1 = *(const s16x8*)(A  + aoff1 + k0);
    s16x8 b0 = *(const s16x8*)(Bt + boff0 + k0);
    s16x8 b1 = *(const s16x8*)(Bt + boff1 + k0);
    __syncthreads();
    *(s16x8*)&As[lrow][lcol]      = a0;
    *(s16x8*)&As[64 + lrow][lcol] = a1;
    *(s16x8*)&Bs[lrow][lcol]      = b0;
    *(s16x8*)&Bs[64 + lrow][lcol] = b1;
    __syncthreads();
    s16x8 af[4], bw[4];
    #pragma unroll
    for (int i = 0; i < 4; i++) af[i] = *(const s16x8*)&As[wr + i*16 + lq][quad*8];
    #pragma unroll
    for (int j = 0; j < 4; j++) bw[j] = *(const s16x8*)&Bs[wc + j*16 + lq][quad*8];
    #pragma unroll
    for (int i = 0; i < 4; i++)
      #pragma unroll
      for (int j = 0; j < 4; j++)
        acc[i][j] = mfma16(af[i], bw[j], acc[i][j]);
  }

  // epilogue: D layout col=lane&15, row=quad*4+reg
  #pragma unroll
  for (int i = 0; i < 4; i++) {
    #pragma unroll
    for (int r = 0; r < 4; r++) {
      int row = by*128 + wr + i*16 + quad*4 + r;
      if (row < M) {
        #pragma unroll
        for (int j = 0; j < 4; j++) {
          int col = bx*128 + wc + j*16 + lq;
          float v = acc[i][j][r] * scale;
          if (BIAS) v += bias[col];
          if (OUT_BF16) ((ushort*)Cv)[(size_t)row*N + col] = f2bf(v);
          else          ((float*)Cv)[(size_t)row*N + col] = v;
        }
      }
    }
  }
}

// ---------------------------------------------------------------------------
// Stage 1 (MFMA): per (64-query tile, frame f, b*h).
// GEMM1 S=Q K_f^T from global frags; softmax in D-layout regs; P -> LDS
// (A-layout round trip); GEMM2 X=P V_f from global Vt frags.
// ---------------------------------------------------------------------------
__global__ __launch_bounds__(256)
void stage1_mfma(const ushort* __restrict__ qbf, const ushort* __restrict__ kvbf,
                 const ushort* __restrict__ Vt, ushort* __restrict__ x)
{
  __shared__ ushort P[4][16*232];   // per-wave 16 rows x 232 (224 used, 16B-aligned rows)

  const int qt = blockIdx.x;   // 0..24
  const int f  = blockIdx.y;   // 0..7
  const int bh = blockIdx.z;   // 0..23
  const int b = bh / NH, h = bh % NH;
  const int tid = threadIdx.x;
  const int w = tid >> 6, lane = tid & 63;
  const int lq = lane & 15, quad = lane >> 4;

  // zero pad cols [208,224) of this wave's P rows
  {
    ushort4 zz; zz.x = 0; zz.y = 0; zz.z = 0; zz.w = 0;
    *(ushort4*)&P[w][lq*232 + 208 + quad*4] = zz;
  }

  // ---- GEMM1: S = Q K^T over 13 n-tiles (196 keys, padded to 208) ----
  int srow = qt*64 + w*16 + lq; if (srow > SEQ-1) srow = SEQ-1;
  const ushort* qp = qbf + ((size_t)b*SEQ + srow)*DIM + h*HD + quad*8;
  s16x8 aq0 = *(const s16x8*)(qp);
  s16x8 aq1 = *(const s16x8*)(qp + 32);

  f32x4 acc[13];
  #pragma unroll
  for (int nt = 0; nt < 13; nt++) {
    int grow = b*SEQ + f*NTOK + nt*16 + lq;
    if (grow > MTOT-1) grow = MTOT-1;
    const ushort* kp = kvbf + (size_t)grow*(2*DIM) + h*HD + quad*8;
    s16x8 bk0 = *(const s16x8*)(kp);
    s16x8 bk1 = *(const s16x8*)(kp + 32);
    f32x4 c = {};
    c = mfma16(aq0, bk0, c);
    c = mfma16(aq1, bk1, c);
    acc[nt] = c;
  }

  // ---- softmax (rows = quad*4+reg, cols = lq across 13 frags) ----
  float mx[4], sm[4];
  #pragma unroll
  for (int r = 0; r < 4; r++) mx[r] = -1e30f;
  #pragma unroll
  for (int nt = 0; nt < 13; nt++) {
    bool valid = (nt < 12) || (lq < 4);
    #pragma unroll
    for (int r = 0; r < 4; r++) {
      float v = valid ? acc[nt][r] : -1e30f;
      acc[nt][r] = v;
      mx[r] = fmaxf(mx[r], v);
    }
  }
  #pragma unroll
  for (int r = 0; r < 4; r++) {
    float m = mx[r];
    m = fmaxf(m, __shfl_xor(m, 1)); m = fmaxf(m, __shfl_xor(m, 2));
    m = fmaxf(m, __shfl_xor(m, 4)); m = fmaxf(m, __shfl_xor(m, 8));
    mx[r] = m; sm[r] = 0.f;
  }
  #pragma unroll
  for (int nt = 0; nt < 13; nt++) {
    #pragma unroll
    for (int r = 0; r < 4; r++) {
      float v = acc[nt][r];
      float e = (v > -1e29f) ? __expf((v - mx[r]) * 0.125f) : 0.f;
      acc[nt][r] = e; sm[r] += e;
    }
  }
  #pragma unroll
  for (int r = 0; r < 4; r++) {
    float s = sm[r];
    s += __shfl_xor(s, 1); s += __shfl_xor(s, 2);
    s += __shfl_xor(s, 4); s += __shfl_xor(s, 8);
    sm[r] = 1.0f / s;
  }
  #pragma unroll
  for (int nt = 0; nt < 13; nt++)
    #pragma unroll
    for (int r = 0; r < 4; r++)
      P[w][(quad*4 + r)*232 + nt*16 + lq] = f2bf(acc[nt][r] * sm[r]);

  __syncthreads();

  // ---- GEMM2: X = P * V (K2 = 224, 7 k-steps; 4 d-tiles) ----
  const ushort* vb = Vt + ((size_t)((b*FR + f)*NH + h)) * (HD*224);
  f32x4 o[4] = {};
  #pragma unroll
  for (int ks = 0; ks < 7; ks++) {
    s16x8 ap = *(const s16x8*)&P[w][lq*232 + ks*32 + quad*8];
    #pragma unroll
    for (int dt = 0; dt < 4; dt++) {
      s16x8 bv = *(const s16x8*)(vb + (size_t)(dt*16 + lq)*224 + ks*32 + quad*8);
      o[dt] = mfma16(ap, bv, o[dt]);
    }
  }

  // ---- store x[b][s][f][h*64+d] bf16 ----
  int s0 = qt*64 + w*16 + quad*4;
  #pragma unroll
  for (int r = 0; r < 4; r++) {
    int s = s0 + r;
    if (s < SEQ) {
      size_t base = (((size_t)b*SEQ + s)*FR + f)*DIM + h*HD;
      #pragma unroll
      for (int dt = 0; dt < 4; dt++)
        x[base + dt*16 + lq] = f2bf(o[dt][r]);
    }
  }
}

// ---------------------------------------------------------------------------
// Stage 2 fused (u-trick) — unchanged from round 2 except z output is bf16.
// ---------------------------------------------------------------------------
__global__ __launch_bounds__(256)
void stage2_fused(const float* __restrict__ q2, const ushort* __restrict__ xbf,
                  const float* __restrict__ Wpkv, ushort* __restrict__ zbf,
                  float* __restrict__ attn2)
{
  __shared__ float q2s[16][64];
  __shared__ float u[16][772];
  __shared__ float lg[16][8];
  __shared__ float a2[16][8];

  const int st = blockIdx.x;
  const int h  = blockIdx.y;
  const int tid = threadIdx.x;
  const int r0 = st * 16;

  for (int i = tid; i < 16*64; i += 256) {
    int t = i >> 6, d = i & 63;
    q2s[t][d] = q2[(size_t)(r0 + t)*DIM + h*HD + d];
  }
  __syncthreads();

  {
    float acc0[16] = {}, acc1[16] = {}, acc2[16] = {};
    const size_t cb = (size_t)h*HD;
    #pragma unroll 4
    for (int d4 = 0; d4 < 64; d4 += 4) {
      float4 w0 = *(const float4*)&Wpkv[(size_t)(tid      )*(2*DIM) + cb + d4];
      float4 w1 = *(const float4*)&Wpkv[(size_t)(tid + 256)*(2*DIM) + cb + d4];
      float4 w2 = *(const float4*)&Wpkv[(size_t)(tid + 512)*(2*DIM) + cb + d4];
      #pragma unroll
      for (int t = 0; t < 16; t++) {
        float4 qv = *(const float4*)&q2s[t][d4];
        acc0[t] += w0.x*qv.x + w0.y*qv.y + w0.z*qv.z + w0.w*qv.w;
        acc1[t] += w1.x*qv.x + w1.y*qv.y + w1.z*qv.z + w1.w*qv.w;
        acc2[t] += w2.x*qv.x + w2.y*qv.y + w2.z*qv.z + w2.w*qv.w;
      }
    }
    #pragma unroll
    for (int t = 0; t < 16; t++) {
      u[t][tid      ] = acc0[t];
      u[t][tid + 256] = acc1[t];
      u[t][tid + 512] = acc2[t];
    }
  }
  __syncthreads();

  if (tid < 128) {
    int t = tid >> 3, f = tid & 7;
    const ushort* xr = xbf + ((size_t)(r0 + t)*FR + f)*DIM;
    float s = 0.f;
    for (int j = 0; j < DIM; j += 4) {
      ushort4 xv = *(const ushort4*)(xr + j);
      float4 uv = *(const float4*)&u[t][j];
      s += bf2f(xv.x)*uv.x + bf2f(xv.y)*uv.y + bf2f(xv.z)*uv.z + bf2f(xv.w)*uv.w;
    }
    lg[t][f] = s;
  }
  __syncthreads();

  if (tid < 16) {
    int t = tid, r = r0 + t;
    int b = r / SEQ, s_ = r % SEQ;
    float m = lg[t][0];
    #pragma unroll
    for (int f = 1; f < 8; f++) m = fmaxf(m, lg[t][f]);
    float e[8]; float sum = 0.f;
    #pragma unroll
    for (int f = 0; f < 8; f++) { e[f] = __expf(lg[t][f] - m); sum += e[f]; }
    float inv = 1.0f / sum;
    float* ao = attn2 + ((size_t)(b*NH + h)*SEQ + s_)*FR;
    #pragma unroll
    for (int f = 0; f < 8; f++) { float a = e[f]*inv; a2[t][f] = a; ao[f] = a; }
  }
  __syncthreads();

  {
    int t = tid >> 4, seg = tid & 15;
    int j0 = seg * 48;
    float yl[48] = {};
    #pragma unroll
    for (int f = 0; f < 8; f++) {
      float af = a2[t][f];
      const ushort* xr = xbf + ((size_t)(r0 + t)*FR + f)*DIM + j0;
      for (int jj = 0; jj < 48; jj += 4) {
        ushort4 xv = *(const ushort4*)(xr + jj);
        yl[jj+0] += af*bf2f(xv.x); yl[jj+1] += af*bf2f(xv.y);
        yl[jj+2] += af*bf2f(xv.z); yl[jj+3] += af*bf2f(xv.w);
      }
    }
    for (int jj = 0; jj < 48; jj++) u[t][j0 + jj] = yl[jj];
  }
  __syncthreads();

  {
    int t = tid >> 4, dq = tid & 15;
    const float* wv = Wpkv + DIM + (size_t)h*HD + dq*4;
    float zx = 0.f, zy = 0.f, zz = 0.f, zw = 0.f;
    #pragma unroll 4
    for (int j = 0; j < DIM; j++) {
      float4 w4 = *(const float4*)(wv + (size_t)j*(2*DIM));
      float yv = u[t][j];
      zx += yv*w4.x; zy += yv*w4.y; zz += yv*w4.z; zw += yv*w4.w;
    }
    ushort4 o; o.x = f2bf(zx); o.y = f2bf(zy); o.z = f2bf(zz); o.w = f2bf(zw);
    *(ushort4*)&zbf[(size_t)(r0 + t)*DIM + h*HD + dq*4] = o;
  }
}

// ---------------------------------------------------------------------------
// Workspace (ushort units; total 68.5 MB, aliased):
//  [xbf 19267584][kvbf 4816896 | q2 fp32 alias][qbf 2408448 | zbf alias]
//  [xqbf 2408448 + xkbf 2408448 | Vt 2752512 alias][WqT][WkvT][WpqT][WprT]
// ---------------------------------------------------------------------------
extern "C" void kernel_launch(void* const* d_in, const int* in_sizes, int n_in,
                              void* d_out, int out_size, void* d_ws, size_t ws_size,
                              hipStream_t stream) {
  const float* xq    = (const float*)d_in[0];
  const float* xk    = (const float*)d_in[1];
  const float* Wq    = (const float*)d_in[2];
  const float* Wkv   = (const float*)d_in[3];
  const float* Wpq   = (const float*)d_in[4];
  const float* Wpkv  = (const float*)d_in[5];
  const float* Wproj = (const float*)d_in[6];
  const float* bproj = (const float*)d_in[7];

  float* out   = (float*)d_out;
  float* attn2 = out + (size_t)MTOT*DIM;

  ushort* ws   = (ushort*)d_ws;
  ushort* xbf  = ws;                          // 3136*8*768
  ushort* kvbf = xbf + (size_t)MTOT*FR*DIM;   // 3136*1536
  float*  q2   = (float*)kvbf;                // alias (same byte size)
  ushort* qbf  = kvbf + (size_t)MTOT*2*DIM;   // 3136*768
  ushort* zbf  = qbf;                         // alias
  ushort* xqbf = qbf + (size_t)MTOT*DIM;      // 3136*768
  ushort* xkbf = xqbf + (size_t)MTOT*DIM;     // 3136*768
  ushort* Vt   = xqbf;                        // alias (2752512 <= 4816896)
  ushort* WqT  = xkbf + (size_t)MTOT*DIM;     // 768*768
  ushort* WkvT = WqT  + (size_t)DIM*DIM;      // 1536*768
  ushort* WpqT = WkvT + (size_t)2*DIM*DIM;    // 768*768
  ushort* WprT = WpqT + (size_t)DIM*DIM;      // 768*768

  dim3 blk(256);
  const int n4 = MTOT*DIM/4;

  cvt_bf16<<<dim3((n4+255)/256), blk, 0, stream>>>(xq, xqbf, n4);
  cvt_bf16<<<dim3((n4+255)/256), blk, 0, stream>>>(xk, xkbf, n4);
  cvt_wT<<<dim3(DIM/64, DIM/64), blk, 0, stream>>>(Wq,    WqT,  DIM,   DIM);
  cvt_wT<<<dim3(2*DIM/64, DIM/64), blk, 0, stream>>>(Wkv, WkvT, 2*DIM, DIM);
  cvt_wT<<<dim3(DIM/64, DIM/64), blk, 0, stream>>>(Wpq,   WpqT, DIM,   DIM);
  cvt_wT<<<dim3(DIM/64, DIM/64), blk, 0, stream>>>(Wproj, WprT, DIM,   DIM);

  // qbf = bf16(xq @ Wq)
  gemm_mfma<true,false,false><<<dim3(DIM/128, (MTOT+127)/128), blk, 0, stream>>>(
      xqbf, WqT, qbf, nullptr, MTOT, DIM, DIM, 1.0f);
  // kvbf = bf16(xk @ Wkv)
  gemm_mfma<true,false,false><<<dim3(2*DIM/128, (MTOT+127)/128), blk, 0, stream>>>(
      xkbf, WkvT, kvbf, nullptr, MTOT, 2*DIM, DIM, 1.0f);
  // Vt
  vtrans<<<dim3(BDIM*FR*NH), blk, 0, stream>>>(kvbf, Vt);
  // stage 1
  stage1_mfma<<<dim3((SEQ+63)/64, FR, BDIM*NH), blk, 0, stream>>>(qbf, kvbf, Vt, xbf);
  // q2 = 0.125 * (x_diag @ Wpq), fp32 out
  gemm_mfma<false,false,true><<<dim3(DIM/128, (MTOT+127)/128), blk, 0, stream>>>(
      xbf, WpqT, q2, nullptr, MTOT, DIM, DIM, 0.125f);
  // stage 2 -> zbf, attn2
  stage2_fused<<<dim3(MTOT/16, NH), blk, 0, stream>>>(q2, xbf, Wpkv, zbf, attn2);
  // out = zbf @ Wproj + bproj
  gemm_mfma<false,true,false><<<dim3(DIM/128, (MTOT+127)/128), blk, 0, stream>>>(
      zbf, WprT, out, bproj, MTOT, DIM, DIM, 1.0f);
}

// Round 4
// 406.562 us; speedup vs baseline: 4.6035x; 2.0850x over previous
//
#include <hip/hip_runtime.h>

#define BDIM 2
#define SEQ  1568
#define DIM  768
#define NH   12
#define FR   8
#define NTOK 196
#define HD   64
#define MTOT (BDIM*SEQ)   // 3136 token rows
#define M2   (MTOT*FR)    // 25088 (t,f) rows for stage-2 GEMMs

typedef __attribute__((ext_vector_type(8))) short s16x8;   // 8 bf16 = 4 VGPRs
typedef __attribute__((ext_vector_type(4))) float f32x4;

static __device__ __forceinline__ float bf2f(ushort u) {
  return __uint_as_float(((unsigned)u) << 16);
}
static __device__ __forceinline__ ushort f2bf(float f) {
  unsigned u = __float_as_uint(f);
  unsigned r = (u + 0x7fffu + ((u >> 16) & 1u)) >> 16;
  return (ushort)r;
}
static __device__ __forceinline__ f32x4 mfma16(s16x8 a, s16x8 b, f32x4 c) {
  return __builtin_amdgcn_mfma_f32_16x16x32_bf16(a, b, c, 0, 0, 0);
}
// async global->LDS, 16B per lane; LDS dest = wave-uniform base + lane*16
static __device__ __forceinline__ void gload_lds16(const ushort* g, ushort* l) {
  __builtin_amdgcn_global_load_lds(
      (const __attribute__((address_space(1))) void*)g,
      (__attribute__((address_space(3))) void*)l, 16, 0, 0);
}

// ---------------------------------------------------------------------------
__global__ __launch_bounds__(256)
void cvt_bf16(const float* __restrict__ in, ushort* __restrict__ out, int n4) {
  int i = blockIdx.x*256 + threadIdx.x;
  if (i < n4) {
    float4 v = ((const float4*)in)[i];
    ushort4 o; o.x = f2bf(v.x); o.y = f2bf(v.y); o.z = f2bf(v.z); o.w = f2bf(v.w);
    ((ushort4*)out)[i] = o;
  }
}

// WT[N][K] = bf16(W[K][N]); 64x64 tiles. grid (N/64, K/64)
__global__ __launch_bounds__(256)
void cvt_wT(const float* __restrict__ W, ushort* __restrict__ WT, int N, int K) {
  __shared__ float T[64][65];
  const int tid = threadIdx.x;
  const int nx = blockIdx.x, ky = blockIdx.y;
  #pragma unroll
  for (int it = 0; it < 4; it++) {
    int idx = it*256 + tid;
    int r = idx >> 4, c4 = (idx & 15) << 2;
    float4 v = *(const float4*)&W[(size_t)(ky*64 + r)*N + nx*64 + c4];
    T[r][c4+0] = v.x; T[r][c4+1] = v.y; T[r][c4+2] = v.z; T[r][c4+3] = v.w;
  }
  __syncthreads();
  #pragma unroll
  for (int it = 0; it < 4; it++) {
    int idx = it*256 + tid;
    int n = idx >> 4, k4 = (idx & 15) << 2;
    ushort4 o;
    o.x = f2bf(T[k4+0][n]); o.y = f2bf(T[k4+1][n]);
    o.z = f2bf(T[k4+2][n]); o.w = f2bf(T[k4+3][n]);
    *(ushort4*)&WT[(size_t)(nx*64 + n)*K + ky*64 + k4] = o;
  }
}

// Vt[(b,f,h)][64][224] bf16, zero-padded n>=196. grid = 192
__global__ __launch_bounds__(256)
void vtrans(const ushort* __restrict__ kvbf, ushort* __restrict__ Vt) {
  __shared__ ushort Vl[NTOK][72];
  const int x = blockIdx.x;
  const int h = x % NH, f = (x / NH) % FR, b = x / (NH*FR);
  const int tid = threadIdx.x;
  for (int idx = tid; idx < NTOK*16; idx += 256) {
    int n = idx >> 4, c4 = (idx & 15) << 2;
    const ushort* p = kvbf + (size_t)(b*SEQ + f*NTOK + n)*(2*DIM) + DIM + h*HD + c4;
    *(ushort4*)&Vl[n][c4] = *(const ushort4*)p;
  }
  __syncthreads();
  ushort* vb = Vt + (size_t)x * (HD*224);
  for (int idx = tid; idx < 64*56; idx += 256) {
    int d = idx / 56, n4 = (idx % 56) << 2;
    ushort4 o;
    o.x = (n4+0 < NTOK) ? Vl[n4+0][d] : (ushort)0;
    o.y = (n4+1 < NTOK) ? Vl[n4+1][d] : (ushort)0;
    o.z = (n4+2 < NTOK) ? Vl[n4+2][d] : (ushort)0;
    o.w = (n4+3 < NTOK) ? Vl[n4+3][d] : (ushort)0;
    *(ushort4*)&vb[(size_t)d*224 + n4] = o;
  }
}

// ---------------------------------------------------------------------------
// bf16 MFMA GEMM, m97 structure: global_load_lds(16B) staging, [128][32] LDS,
// 2-barrier K-loop. Tile 128x128, BK=32, 256 threads, 2x2 waves x 4x4 frags.
// EPI: 0 = store C (OUT_BF16/BIAS/scale apply)
//      1 = logits: Lg[row*12 + head] = sum_col D[row][col]*q2[t][col] (per-head)
//      2 = zsum:   z[t][col] = sum_f D[(t,f)][col]*a2[t][h(col)][f]  (bf16)
// ---------------------------------------------------------------------------
template<int EPI, bool OUT_BF16, bool BIAS, bool DIAG>
__global__ __launch_bounds__(256)
void gemm_mfma(const ushort* __restrict__ A, const ushort* __restrict__ Bt,
               void* __restrict__ Cv, const float* __restrict__ bias,
               const float* __restrict__ q2g, const float* __restrict__ a2g,
               int M, int N, int K, float scale)
{
  __shared__ ushort As[128][32];
  __shared__ ushort Bs[128][32];
  extern __shared__ char dynlds[];     // EPI1: 8KB q2s; EPI2: 1KB a2s

  const int tid = threadIdx.x;
  const int bx = blockIdx.x, by = blockIdx.y;
  const int w = tid >> 6, lane = tid & 63;
  const int lq = lane & 15, quad = lane >> 4;
  const int wr = (w >> 1) * 64, wc = (w & 1) * 64;

  // staging map: thread tid -> row tid>>2, col (tid&3)*8 == LDS byte off 16*tid
  const int lrow = tid >> 2, lcol = (tid & 3) << 3;
  int ar0 = by*128 + lrow;       if (ar0 > M-1) ar0 = M-1;
  int ar1 = by*128 + 64 + lrow;  if (ar1 > M-1) ar1 = M-1;
  size_t aoff0, aoff1;
  if (DIAG) {
    int f0 = (ar0 % SEQ) / NTOK, f1 = (ar1 % SEQ) / NTOK;
    aoff0 = ((size_t)ar0*FR + f0)*DIM + lcol;
    aoff1 = ((size_t)ar1*FR + f1)*DIM + lcol;
  } else {
    aoff0 = (size_t)ar0*K + lcol;
    aoff1 = (size_t)ar1*K + lcol;
  }
  const size_t boff0 = (size_t)(bx*128 + lrow)*K + lcol;
  const size_t boff1 = (size_t)(bx*128 + 64 + lrow)*K + lcol;
  ushort* ldsA0 = &As[(w*16)][0];
  ushort* ldsA1 = &As[64 + w*16][0];
  ushort* ldsB0 = &Bs[(w*16)][0];
  ushort* ldsB1 = &Bs[64 + w*16][0];

  // epilogue operand pre-loads (visible via in-loop barriers)
  if (EPI == 1) {
    float* q2s = (float*)dynlds;                       // [16][128]
    int tt = tid >> 4, c0 = (tid & 15) << 3;
    const float* src = q2g + (size_t)(by*16 + tt)*DIM + bx*128 + c0;
    *(float4*)&q2s[tt*128 + c0]     = *(const float4*)src;
    *(float4*)&q2s[tt*128 + c0 + 4] = *(const float4*)(src + 4);
  }
  if (EPI == 2) {
    float* a2s = (float*)dynlds;                       // [16][16] = [t][h2*8+f]
    int tt = tid >> 4, idx = tid & 15;                 // idx = hh*8+f
    a2s[tt*16 + idx] =
        a2g[((size_t)(by*16 + tt)*NH + bx*2 + (idx >> 3))*FR + (idx & 7)];
  }

  f32x4 acc[4][4] = {};

  for (int k0 = 0; k0 < K; k0 += 32) {
    __syncthreads();                 // prior frag reads done before DMA overwrite
    gload_lds16(A  + aoff0 + k0, ldsA0);
    gload_lds16(A  + aoff1 + k0, ldsA1);
    gload_lds16(Bt + boff0 + k0, ldsB0);
    gload_lds16(Bt + boff1 + k0, ldsB1);
    __syncthreads();                 // drains vmcnt(0): DMA complete
    s16x8 af[4], bw[4];
    #pragma unroll
    for (int i = 0; i < 4; i++) af[i] = *(const s16x8*)&As[wr + i*16 + lq][quad*8];
    #pragma unroll
    for (int j = 0; j < 4; j++) bw[j] = *(const s16x8*)&Bs[wc + j*16 + lq][quad*8];
    #pragma unroll
    for (int i = 0; i < 4; i++)
      #pragma unroll
      for (int j = 0; j < 4; j++)
        acc[i][j] = mfma16(af[i], bw[j], acc[i][j]);
  }

  if (EPI == 0) {
    #pragma unroll
    for (int i = 0; i < 4; i++) {
      #pragma unroll
      for (int r = 0; r < 4; r++) {
        int row = by*128 + wr + i*16 + quad*4 + r;
        if (row < M) {
          #pragma unroll
          for (int j = 0; j < 4; j++) {
            int col = bx*128 + wc + j*16 + lq;
            float v = acc[i][j][r] * scale;
            if (BIAS) v += bias[col];
            if (OUT_BF16) ((ushort*)Cv)[(size_t)row*N + col] = f2bf(v);
            else          ((float*)Cv)[(size_t)row*N + col] = v;
          }
        }
      }
    }
  } else if (EPI == 1) {
    // logits: head = bx*2 + (wc>>6); dot over the head's 64 cols
    const float* q2s = (const float*)dynlds;
    float* Lg = (float*)Cv;
    const int head = bx*2 + (wc >> 6);
    #pragma unroll
    for (int i = 0; i < 4; i++) {
      #pragma unroll
      for (int r = 0; r < 4; r++) {
        int rl = wr + i*16 + quad*4 + r;     // 0..127
        int tt = rl >> 3;
        float p = 0.f;
        #pragma unroll
        for (int j = 0; j < 4; j++)
          p += acc[i][j][r] * q2s[tt*128 + wc + j*16 + lq];
        p += __shfl_xor(p, 1); p += __shfl_xor(p, 2);
        p += __shfl_xor(p, 4); p += __shfl_xor(p, 8);
        if (lq == 0)
          Lg[(size_t)(by*128 + rl)*NH + head] = p;
      }
    }
  } else {
    // zsum: weight rows by a2[t][h][f], reduce the 8 f-rows per token
    const float* a2s = (const float*)dynlds;
    ushort* zo = (ushort*)Cv;
    const int hh = wc >> 6;
    #pragma unroll
    for (int i = 0; i < 4; i++) {
      float zj[4] = {};
      #pragma unroll
      for (int r = 0; r < 4; r++) {
        int rl = wr + i*16 + quad*4 + r;
        int tt = rl >> 3, f = rl & 7;
        float a = a2s[tt*16 + hh*8 + f];
        #pragma unroll
        for (int j = 0; j < 4; j++) zj[j] += acc[i][j][r] * a;
      }
      #pragma unroll
      for (int j = 0; j < 4; j++) zj[j] += __shfl_xor(zj[j], 16);
      if ((quad & 1) == 0) {                  // quad 0 -> token a, quad 2 -> token b
        int tg = by*16 + ((wr + i*16 + quad*4) >> 3);
        #pragma unroll
        for (int j = 0; j < 4; j++) {
          int col = bx*128 + wc + j*16 + lq;
          zo[(size_t)tg*DIM + col] = f2bf(zj[j]);
        }
      }
    }
  }
}

// ---------------------------------------------------------------------------
// Stage 1 (MFMA): per (64-query tile, frame f, b*h). Unchanged from round 3.
// ---------------------------------------------------------------------------
__global__ __launch_bounds__(256)
void stage1_mfma(const ushort* __restrict__ qbf, const ushort* __restrict__ kvbf,
                 const ushort* __restrict__ Vt, ushort* __restrict__ x)
{
  __shared__ ushort P[4][16*232];

  const int qt = blockIdx.x;
  const int f  = blockIdx.y;
  const int bh = blockIdx.z;
  const int b = bh / NH, h = bh % NH;
  const int tid = threadIdx.x;
  const int w = tid >> 6, lane = tid & 63;
  const int lq = lane & 15, quad = lane >> 4;

  {
    ushort4 zz; zz.x = 0; zz.y = 0; zz.z = 0; zz.w = 0;
    *(ushort4*)&P[w][lq*232 + 208 + quad*4] = zz;
  }

  int srow = qt*64 + w*16 + lq; if (srow > SEQ-1) srow = SEQ-1;
  const ushort* qp = qbf + ((size_t)b*SEQ + srow)*DIM + h*HD + quad*8;
  s16x8 aq0 = *(const s16x8*)(qp);
  s16x8 aq1 = *(const s16x8*)(qp + 32);

  f32x4 acc[13];
  #pragma unroll
  for (int nt = 0; nt < 13; nt++) {
    int grow = b*SEQ + f*NTOK + nt*16 + lq;
    if (grow > MTOT-1) grow = MTOT-1;
    const ushort* kp = kvbf + (size_t)grow*(2*DIM) + h*HD + quad*8;
    s16x8 bk0 = *(const s16x8*)(kp);
    s16x8 bk1 = *(const s16x8*)(kp + 32);
    f32x4 c = {};
    c = mfma16(aq0, bk0, c);
    c = mfma16(aq1, bk1, c);
    acc[nt] = c;
  }

  float mx[4], sm[4];
  #pragma unroll
  for (int r = 0; r < 4; r++) mx[r] = -1e30f;
  #pragma unroll
  for (int nt = 0; nt < 13; nt++) {
    bool valid = (nt < 12) || (lq < 4);
    #pragma unroll
    for (int r = 0; r < 4; r++) {
      float v = valid ? acc[nt][r] : -1e30f;
      acc[nt][r] = v;
      mx[r] = fmaxf(mx[r], v);
    }
  }
  #pragma unroll
  for (int r = 0; r < 4; r++) {
    float m = mx[r];
    m = fmaxf(m, __shfl_xor(m, 1)); m = fmaxf(m, __shfl_xor(m, 2));
    m = fmaxf(m, __shfl_xor(m, 4)); m = fmaxf(m, __shfl_xor(m, 8));
    mx[r] = m; sm[r] = 0.f;
  }
  #pragma unroll
  for (int nt = 0; nt < 13; nt++) {
    #pragma unroll
    for (int r = 0; r < 4; r++) {
      float v = acc[nt][r];
      float e = (v > -1e29f) ? __expf((v - mx[r]) * 0.125f) : 0.f;
      acc[nt][r] = e; sm[r] += e;
    }
  }
  #pragma unroll
  for (int r = 0; r < 4; r++) {
    float s = sm[r];
    s += __shfl_xor(s, 1); s += __shfl_xor(s, 2);
    s += __shfl_xor(s, 4); s += __shfl_xor(s, 8);
    sm[r] = 1.0f / s;
  }
  #pragma unroll
  for (int nt = 0; nt < 13; nt++)
    #pragma unroll
    for (int r = 0; r < 4; r++)
      P[w][(quad*4 + r)*232 + nt*16 + lq] = f2bf(acc[nt][r] * sm[r]);

  __syncthreads();

  const ushort* vb = Vt + ((size_t)((b*FR + f)*NH + h)) * (HD*224);
  f32x4 o[4] = {};
  #pragma unroll
  for (int ks = 0; ks < 7; ks++) {
    s16x8 ap = *(const s16x8*)&P[w][lq*232 + ks*32 + quad*8];
    #pragma unroll
    for (int dt = 0; dt < 4; dt++) {
      s16x8 bv = *(const s16x8*)(vb + (size_t)(dt*16 + lq)*224 + ks*32 + quad*8);
      o[dt] = mfma16(ap, bv, o[dt]);
    }
  }

  int s0 = qt*64 + w*16 + quad*4;
  #pragma unroll
  for (int r = 0; r < 4; r++) {
    int s = s0 + r;
    if (s < SEQ) {
      size_t base = (((size_t)b*SEQ + s)*FR + f)*DIM + h*HD;
      #pragma unroll
      for (int dt = 0; dt < 4; dt++)
        x[base + dt*16 + lq] = f2bf(o[dt][r]);
    }
  }
}

// ---------------------------------------------------------------------------
// Stage 2 softmax: Lg[(t*8+f)*12+h] -> attn2 (output) + a2buf[t][h][f]
// ---------------------------------------------------------------------------
__global__ __launch_bounds__(256)
void stage2_softmax(const float* __restrict__ Lg, float* __restrict__ attn2,
                    float* __restrict__ a2buf)
{
  int gid = blockIdx.x*256 + threadIdx.x;
  if (gid >= MTOT*NH) return;
  int t = gid / NH, h = gid % NH;
  int b = t / SEQ, s = t % SEQ;
  float v[8], m = -1e30f;
  #pragma unroll
  for (int f = 0; f < 8; f++) {
    v[f] = Lg[(size_t)(t*FR + f)*NH + h];
    m = fmaxf(m, v[f]);
  }
  float sum = 0.f;
  #pragma unroll
  for (int f = 0; f < 8; f++) { v[f] = __expf(v[f] - m); sum += v[f]; }
  float inv = 1.0f / sum;
  float* ao = attn2 + ((size_t)(b*NH + h)*SEQ + s)*FR;
  float* ab = a2buf + (size_t)gid*FR;
  #pragma unroll
  for (int f = 0; f < 8; f++) {
    float a = v[f] * inv;
    ao[f] = a; ab[f] = a;
  }
}

// ---------------------------------------------------------------------------
// Workspace (ushort units; 68.5 MB total, same as the known-good round-2 map):
//  xbf   @0         19267584
//  kvbf  @19267584   4816896  | q2 (fp32) alias after stage1
//  qbf   @24084480   2408448  | zbf alias after stage1
//  xqbf  @26492928   2408448  | Vt alias (spans into xkbf) | Lg+a2buf alias after stage1
//  xkbf  @28901376   2408448
//  WqT   @31309824    589824
//  WkvT  @31899648   1179648  | WpkvT alias after kv GEMM
//  WpqT  @33079296    589824
//  WprT  @33669120    589824
// ---------------------------------------------------------------------------
extern "C" void kernel_launch(void* const* d_in, const int* in_sizes, int n_in,
                              void* d_out, int out_size, void* d_ws, size_t ws_size,
                              hipStream_t stream) {
  const float* xq    = (const float*)d_in[0];
  const float* xk    = (const float*)d_in[1];
  const float* Wq    = (const float*)d_in[2];
  const float* Wkv   = (const float*)d_in[3];
  const float* Wpq   = (const float*)d_in[4];
  const float* Wpkv  = (const float*)d_in[5];
  const float* Wproj = (const float*)d_in[6];
  const float* bproj = (const float*)d_in[7];

  float* out   = (float*)d_out;
  float* attn2 = out + (size_t)MTOT*DIM;

  ushort* ws    = (ushort*)d_ws;
  ushort* xbf   = ws;
  ushort* kvbf  = xbf + (size_t)MTOT*FR*DIM;
  float*  q2    = (float*)kvbf;                 // alias, post-stage1
  ushort* qbf   = kvbf + (size_t)MTOT*2*DIM;
  ushort* zbf   = qbf;                          // alias, post-stage1
  ushort* xqbf  = qbf + (size_t)MTOT*DIM;
  ushort* xkbf  = xqbf + (size_t)MTOT*DIM;
  ushort* Vt    = xqbf;                         // alias (2752512 <= 4816896)
  float*  Lg    = (float*)xqbf;                 // alias, post-stage1 (301056 fl)
  float*  a2buf = Lg + (size_t)M2*NH;           // 301056 fl, still inside xqbf
  ushort* WqT   = xkbf + (size_t)MTOT*DIM;
  ushort* WkvT  = WqT  + (size_t)DIM*DIM;
  ushort* WpkvT = WkvT;                         // alias, post-kv-GEMM
  ushort* WpqT  = WkvT + (size_t)2*DIM*DIM;
  ushort* WprT  = WpqT + (size_t)DIM*DIM;

  dim3 blk(256);
  const int n4 = MTOT*DIM/4;

  cvt_bf16<<<dim3((n4+255)/256), blk, 0, stream>>>(xq, xqbf, n4);
  cvt_bf16<<<dim3((n4+255)/256), blk, 0, stream>>>(xk, xkbf, n4);
  cvt_wT<<<dim3(DIM/64, DIM/64), blk, 0, stream>>>(Wq,    WqT,  DIM,   DIM);
  cvt_wT<<<dim3(2*DIM/64, DIM/64), blk, 0, stream>>>(Wkv, WkvT, 2*DIM, DIM);
  cvt_wT<<<dim3(DIM/64, DIM/64), blk, 0, stream>>>(Wpq,   WpqT, DIM,   DIM);
  cvt_wT<<<dim3(DIM/64, DIM/64), blk, 0, stream>>>(Wproj, WprT, DIM,   DIM);

  // q = xq @ Wq (bf16 out)
  gemm_mfma<0,true,false,false><<<dim3(DIM/128, (MTOT+127)/128), blk, 0, stream>>>(
      xqbf, WqT, qbf, nullptr, nullptr, nullptr, MTOT, DIM, DIM, 1.0f);
  // kv = xk @ Wkv (bf16 out)
  gemm_mfma<0,true,false,false><<<dim3(2*DIM/128, (MTOT+127)/128), blk, 0, stream>>>(
      xkbf, WkvT, kvbf, nullptr, nullptr, nullptr, MTOT, 2*DIM, DIM, 1.0f);
  // WpkvT (aliases WkvT; safe after kv GEMM)
  cvt_wT<<<dim3(2*DIM/64, DIM/64), blk, 0, stream>>>(Wpkv, WpkvT, 2*DIM, DIM);
  // Vt (aliases xqbf; safe after q/kv GEMMs)
  vtrans<<<dim3(BDIM*FR*NH), blk, 0, stream>>>(kvbf, Vt);
  // stage 1 -> xbf
  stage1_mfma<<<dim3((SEQ+63)/64, FR, BDIM*NH), blk, 0, stream>>>(qbf, kvbf, Vt, xbf);
  // q2 = 0.125 * (x_diag @ Wpq), fp32 (aliases kvbf)
  gemm_mfma<0,false,false,true><<<dim3(DIM/128, (MTOT+127)/128), blk, 0, stream>>>(
      xbf, WpqT, q2, nullptr, nullptr, nullptr, MTOT, DIM, DIM, 0.125f);
  // logits: (x @ Wk) dotted with q2 in-epilogue -> Lg  (k2 never materialized)
  gemm_mfma<1,false,false,false><<<dim3(DIM/128, M2/128), blk, 8192, stream>>>(
      xbf, WpkvT, Lg, nullptr, q2, nullptr, M2, DIM, DIM, 1.0f);
  // softmax -> attn2 (output) + a2buf
  stage2_softmax<<<dim3((MTOT*NH+255)/256), blk, 0, stream>>>(Lg, attn2, a2buf);
  // z: (x @ Wv) f-reduced with a2 in-epilogue -> zbf  (v2 never materialized)
  gemm_mfma<2,false,false,false><<<dim3(DIM/128, M2/128), blk, 1024, stream>>>(
      xbf, WpkvT + (size_t)DIM*DIM, zbf, nullptr, nullptr, a2buf, M2, DIM, DIM, 1.0f);
  // out = z @ Wproj + bproj (fp32 out)
  gemm_mfma<0,false,true,false><<<dim3(DIM/128, (MTOT+127)/128), blk, 0, stream>>>(
      zbf, WprT, out, bproj, nullptr, nullptr, MTOT, DIM, DIM, 1.0f);
}